// Round 1
// baseline (179.856 us; speedup 1.0000x reference)
//
#include <hip/hip_runtime.h>
#include <hip/hip_bf16.h>

// Grouped GEMM: out[e,s,o] = sum_i x[e,s,i] * w[e,o,i]
// E=8, S=8192 tokens/expert, O=512, I=1024, fp32 in/out, bf16 MFMA compute.

#define NE 8
#define NO 512
#define NI 1024
#define NS 8192

#define BM 128
#define BN 128
#define BK 64
#define NT (NI / BK)  // 16 K-steps

typedef __attribute__((ext_vector_type(4))) float f32x4;
typedef __attribute__((ext_vector_type(8))) short short8;

__device__ __forceinline__ short8 cvt8(f32x4 a, f32x4 b) {
    short8 r;
    r[0] = (short)__builtin_bit_cast(unsigned short, __float2bfloat16(a[0]));
    r[1] = (short)__builtin_bit_cast(unsigned short, __float2bfloat16(a[1]));
    r[2] = (short)__builtin_bit_cast(unsigned short, __float2bfloat16(a[2]));
    r[3] = (short)__builtin_bit_cast(unsigned short, __float2bfloat16(a[3]));
    r[4] = (short)__builtin_bit_cast(unsigned short, __float2bfloat16(b[0]));
    r[5] = (short)__builtin_bit_cast(unsigned short, __float2bfloat16(b[1]));
    r[6] = (short)__builtin_bit_cast(unsigned short, __float2bfloat16(b[2]));
    r[7] = (short)__builtin_bit_cast(unsigned short, __float2bfloat16(b[3]));
    return r;
}

__global__ __launch_bounds__(256, 2)
void moe_grouped_gemm(const float* __restrict__ X,
                      const float* __restrict__ W,
                      float* __restrict__ Out) {
    // 2048 blocks = 8 experts * 64 mblks * 4 nblks.
    // XCD-chunk swizzle (nwg % 8 == 0, bijective): each XCD owns one expert.
    int bid  = blockIdx.x;
    int swz  = (bid & 7) * 256 + (bid >> 3);
    int e    = swz >> 8;
    int rem  = swz & 255;
    int mblk = rem >> 2;   // nblk inner: 4 siblings share the same A tile
    int nblk = rem & 3;

    const float* Ap = X   + ((size_t)e * NS + (size_t)mblk * BM) * NI;
    const float* Bp = W   + ((size_t)e * NO + (size_t)nblk * BN) * NI;
    float*       Cp = Out + ((size_t)e * NS + (size_t)mblk * BM) * NO + nblk * BN;

    __shared__ short lA[2][BM * BK];
    __shared__ short lB[2][BN * BK];

    const int tid  = threadIdx.x;
    const int lane = tid & 63;
    const int wid  = tid >> 6;
    const int wr   = (wid >> 1) * 64;   // wave row base (2x2 wave grid)
    const int wc   = (wid & 1) * 64;    // wave col base
    const int l15  = lane & 15;
    const int l4   = lane >> 4;

    f32x4 acc[4][4];
#pragma unroll
    for (int i = 0; i < 4; ++i)
#pragma unroll
        for (int j = 0; j < 4; ++j)
            acc[i][j] = (f32x4){0.f, 0.f, 0.f, 0.f};

    // Staging chunks: q = tid + i*256 -> (row q>>3, col-chunk q&7), 8 floats each.
    int qr[4], qc[4], wofs[4];
#pragma unroll
    for (int i = 0; i < 4; ++i) {
        int q  = tid + i * 256;
        qr[i]  = q >> 3;
        qc[i]  = q & 7;
        // T2 XOR swizzle on the 16B-chunk index (shorts): elem = row*64 + ((cc ^ (row&7))<<3)
        wofs[i] = qr[i] * BK + (((qc[i] ^ (qr[i] & 7))) << 3);
    }

    f32x4 la[4][2], lb[4][2];

#define LOADT(kt)                                                              \
    do {                                                                       \
        const float* ab = Ap + (kt) * BK;                                      \
        const float* bb = Bp + (kt) * BK;                                      \
        _Pragma("unroll") for (int i = 0; i < 4; ++i) {                        \
            const f32x4* pa = (const f32x4*)(ab + (size_t)qr[i] * NI + qc[i] * 8); \
            la[i][0] = pa[0];                                                  \
            la[i][1] = pa[1];                                                  \
            const f32x4* pb = (const f32x4*)(bb + (size_t)qr[i] * NI + qc[i] * 8); \
            lb[i][0] = pb[0];                                                  \
            lb[i][1] = pb[1];                                                  \
        }                                                                      \
    } while (0)

#define STAGE(buf)                                                             \
    do {                                                                       \
        _Pragma("unroll") for (int i = 0; i < 4; ++i) {                        \
            *(short8*)&lA[buf][wofs[i]] = cvt8(la[i][0], la[i][1]);            \
            *(short8*)&lB[buf][wofs[i]] = cvt8(lb[i][0], lb[i][1]);            \
        }                                                                      \
    } while (0)

#define COMPUTE(buf)                                                           \
    do {                                                                       \
        _Pragma("unroll") for (int kk = 0; kk < 2; ++kk) {                     \
            short8 af[4], bf_[4];                                              \
            _Pragma("unroll") for (int mi = 0; mi < 4; ++mi) {                 \
                int row = wr + mi * 16 + l15;                                  \
                int cc  = ((kk * 4 + l4) ^ (row & 7)) << 3;                    \
                af[mi]  = *(const short8*)&lA[buf][row * BK + cc];             \
            }                                                                  \
            _Pragma("unroll") for (int ni = 0; ni < 4; ++ni) {                 \
                int row = wc + ni * 16 + l15;                                  \
                int cc  = ((kk * 4 + l4) ^ (row & 7)) << 3;                    \
                bf_[ni] = *(const short8*)&lB[buf][row * BK + cc];             \
            }                                                                  \
            _Pragma("unroll") for (int mi = 0; mi < 4; ++mi)                   \
                _Pragma("unroll") for (int ni = 0; ni < 4; ++ni)               \
                    acc[mi][ni] = __builtin_amdgcn_mfma_f32_16x16x32_bf16(     \
                        af[mi], bf_[ni], acc[mi][ni], 0, 0, 0);                \
        }                                                                      \
    } while (0)

    LOADT(0);
    STAGE(0);
    __syncthreads();
    int cur = 0;
#pragma unroll 1
    for (int kt = 0; kt < NT; ++kt) {
        if (kt + 1 < NT) LOADT(kt + 1);      // issue next-tile loads early (T14-lite)
        COMPUTE(cur);
        if (kt + 1 < NT) STAGE(cur ^ 1);     // convert + ds_write after compute
        __syncthreads();                     // one barrier per K-step (double buffer)
        cur ^= 1;
    }

    // Epilogue: D[m][n], m = (lane>>4)*4 + r, n = lane&15 within each 16x16 frag.
#pragma unroll
    for (int mi = 0; mi < 4; ++mi) {
#pragma unroll
        for (int r = 0; r < 4; ++r) {
            int row   = wr + mi * 16 + l4 * 4 + r;
            float* cp = Cp + (size_t)row * NO + wc + l15;
#pragma unroll
            for (int ni = 0; ni < 4; ++ni)
                cp[ni * 16] = acc[mi][ni][r];
        }
    }
#undef LOADT
#undef STAGE
#undef COMPUTE
}

extern "C" void kernel_launch(void* const* d_in, const int* in_sizes, int n_in,
                              void* d_out, int out_size, void* d_ws, size_t ws_size,
                              hipStream_t stream) {
    const float* X = (const float*)d_in[0];
    const float* W = (const float*)d_in[1];
    float* Out     = (float*)d_out;
    // d_in[2] (expert_size) is static == 8192; layout is compile-time.
    dim3 grid(NE * (NS / BM) * (NO / BN));  // 2048
    dim3 block(256);
    hipLaunchKernelGGL(moe_grouped_gemm, grid, block, 0, stream, X, W, Out);
}